// Round 10
// baseline (493.432 us; speedup 1.0000x reference)
//
#include <hip/hip_runtime.h>
#include <hip/hip_cooperative_groups.h>

namespace cg = cooperative_groups;

#define DT 0.01f

// Native 4-float vector for nontemporal builtins (HIP's float4 is a class
// type, which __builtin_nontemporal_store rejects).
typedef float f32x4 __attribute__((ext_vector_type(4)));

// ===================== Fused cooperative kernel =============================
// Decomposition: C chunks x L rows, nSlice channel-slices of 1024 channels
// (256 threads x 4 ch). Grid = C*nSlice blocks, 256 threads.
// Phase1: per-(chunk,slice) aggregate with zero init -> B[c][ch].
// Phase2: (16 blocks) per-channel serial prefix over C chunks, in-place.
// Phase3: rescan from true chunk-entry state, add bias, nontemporal store.
__global__ __launch_bounds__(256, 4) void fol_fused(
        const float* __restrict__ in, const float* __restrict__ tau,
        const float* __restrict__ bias, float* __restrict__ out,
        float* __restrict__ B, int N4, int C, int L, int nSlice, int nChBlk) {
    cg::grid_group grid = cg::this_grid();

    const int tid = threadIdx.x;
    const int c  = blockIdx.x / nSlice;
    const int sl = blockIdx.x % nSlice;
    const int ch4 = sl * 256 + tid;

    const float4 tv = reinterpret_cast<const float4*>(tau)[ch4];
    const float ax = DT / fmaxf(tv.x, DT), ay = DT / fmaxf(tv.y, DT),
                az = DT / fmaxf(tv.z, DT), aw = DT / fmaxf(tv.w, DT);
    const float qx = 1.f - ax, qy = 1.f - ay, qz = 1.f - az, qw = 1.f - aw;

    // ---------------- Phase 1: local aggregate (zero initial state) ---------
    {
        const float4* p = reinterpret_cast<const float4*>(in) + (size_t)c * L * N4 + ch4;
        float sx = 0.f, sy = 0.f, sz = 0.f, sw = 0.f;
        float4 x[8];
        for (int h = 0; h < L; h += 8) {
            #pragma unroll
            for (int j = 0; j < 8; ++j) x[j] = p[(size_t)(h + j) * N4];
            #pragma unroll
            for (int j = 0; j < 8; ++j) {
                sx = fmaf(qx, sx, ax * x[j].x);
                sy = fmaf(qy, sy, ay * x[j].y);
                sz = fmaf(qz, sz, az * x[j].z);
                sw = fmaf(qw, sw, aw * x[j].w);
            }
        }
        reinterpret_cast<float4*>(B)[(size_t)c * N4 + ch4] = make_float4(sx, sy, sz, sw);
    }

    grid.sync();

    // ---------------- Phase 2: prefix over chunks (16 blocks active) --------
    if ((int)blockIdx.x < nChBlk) {
        const int ch = blockIdx.x * 256 + tid;
        const int N = N4 * 4;
        const float a = DT / fmaxf(tau[ch], DT);
        const float q = 1.f - a;
        float qL = 1.f, bb = q;
        int e = L;
        while (e) { if (e & 1) qL *= bb; bb *= bb; e >>= 1; }

        float S = in[ch];  // s_0 = input[0]

        constexpr int BATCH = 16;
        float x[BATCH], xn[BATCH];
        #pragma unroll
        for (int j = 0; j < BATCH; ++j) x[j] = B[(size_t)j * N + ch];

        for (int cb = 0; cb < C; cb += BATCH) {
            const int nb = cb + BATCH;
            if (nb < C) {
                #pragma unroll
                for (int j = 0; j < BATCH; ++j) xn[j] = B[(size_t)(nb + j) * N + ch];
            }
            #pragma unroll
            for (int j = 0; j < BATCH; ++j) {
                B[(size_t)(cb + j) * N + ch] = S;   // publish chunk-entry state
                S = fmaf(qL, S, x[j]);              // advance one chunk
            }
            #pragma unroll
            for (int j = 0; j < BATCH; ++j) x[j] = xn[j];
        }
    }

    grid.sync();

    // ---------------- Phase 3: rescan from true state, write out ------------
    {
        const float4 bv = reinterpret_cast<const float4*>(bias)[ch4];
        const float4 sv = reinterpret_cast<const float4*>(B)[(size_t)c * N4 + ch4];
        float sx = sv.x, sy = sv.y, sz = sv.z, sw = sv.w;

        const float4* p = reinterpret_cast<const float4*>(in) + (size_t)c * L * N4 + ch4;
        f32x4*       o = reinterpret_cast<f32x4*>(out)        + (size_t)c * L * N4 + ch4;
        float4 x[8];
        for (int h = 0; h < L; h += 8) {
            #pragma unroll
            for (int j = 0; j < 8; ++j) x[j] = p[(size_t)(h + j) * N4];
            #pragma unroll
            for (int j = 0; j < 8; ++j) {
                sx = fmaf(qx, sx, ax * x[j].x);
                sy = fmaf(qy, sy, ay * x[j].y);
                sz = fmaf(qz, sz, az * x[j].z);
                sw = fmaf(qw, sw, aw * x[j].w);
                f32x4 ov; ov.x = sx + bv.x; ov.y = sy + bv.y; ov.z = sz + bv.z; ov.w = sw + bv.w;
                __builtin_nontemporal_store(ov, &o[(size_t)(h + j) * N4]);
            }
        }
    }
}

// ================= Fallback: proven 3-kernel path (R7: 271 µs) =============

__global__ __launch_bounds__(256) void fol_pass1_L16(
        const float* __restrict__ in, const float* __restrict__ tau,
        float* __restrict__ B, int N4) {
    const int chunk = blockIdx.y;
    const int ch4 = blockIdx.x * 256 + threadIdx.x;
    if (ch4 >= N4) return;
    const float4* p = reinterpret_cast<const float4*>(in) + (size_t)chunk * 16 * N4 + ch4;
    float4 x[16];
    #pragma unroll
    for (int t = 0; t < 16; ++t) x[t] = p[(size_t)t * N4];
    const float4 tv = reinterpret_cast<const float4*>(tau)[ch4];
    const float ax = DT / fmaxf(tv.x, DT), ay = DT / fmaxf(tv.y, DT),
                az = DT / fmaxf(tv.z, DT), aw = DT / fmaxf(tv.w, DT);
    const float qx = 1.f - ax, qy = 1.f - ay, qz = 1.f - az, qw = 1.f - aw;
    float sx = 0.f, sy = 0.f, sz = 0.f, sw = 0.f;
    #pragma unroll
    for (int t = 0; t < 16; ++t) {
        sx = fmaf(qx, sx, ax * x[t].x);
        sy = fmaf(qy, sy, ay * x[t].y);
        sz = fmaf(qz, sz, az * x[t].z);
        sw = fmaf(qw, sw, aw * x[t].w);
    }
    reinterpret_cast<float4*>(B)[(size_t)chunk * N4 + ch4] = make_float4(sx, sy, sz, sw);
}

__global__ __launch_bounds__(256) void fol_pass2_pipe(
        const float* __restrict__ in, const float* __restrict__ tau,
        float* __restrict__ B, int N, int C, int L) {
    const int ch = blockIdx.x * 256 + threadIdx.x;
    if (ch >= N) return;
    const float a = DT / fmaxf(tau[ch], DT);
    const float q = 1.f - a;
    float qL = 1.f, b = q;
    int e = L;
    while (e) { if (e & 1) qL *= b; b *= b; e >>= 1; }
    float S = in[ch];
    constexpr int BATCH = 32;
    float x[BATCH], xn[BATCH];
    #pragma unroll
    for (int j = 0; j < BATCH; ++j) x[j] = B[(size_t)j * N + ch];
    for (int cb = 0; cb < C; cb += BATCH) {
        const int nb = cb + BATCH;
        if (nb < C) {
            #pragma unroll
            for (int j = 0; j < BATCH; ++j) xn[j] = B[(size_t)(nb + j) * N + ch];
        }
        #pragma unroll
        for (int j = 0; j < BATCH; ++j) {
            B[(size_t)(cb + j) * N + ch] = S;
            S = fmaf(qL, S, x[j]);
        }
        #pragma unroll
        for (int j = 0; j < BATCH; ++j) x[j] = xn[j];
    }
}

__global__ __launch_bounds__(256) void fol_pass3_L16(
        const float* __restrict__ in, const float* __restrict__ tau,
        const float* __restrict__ bias, const float* __restrict__ S,
        float* __restrict__ out, int N4) {
    const int chunk = blockIdx.y;
    const int ch4 = blockIdx.x * 256 + threadIdx.x;
    if (ch4 >= N4) return;
    const float4* p = reinterpret_cast<const float4*>(in) + (size_t)chunk * 16 * N4 + ch4;
    float4 x[16];
    #pragma unroll
    for (int t = 0; t < 16; ++t) x[t] = p[(size_t)t * N4];
    const float4 tv = reinterpret_cast<const float4*>(tau)[ch4];
    const float4 bv = reinterpret_cast<const float4*>(bias)[ch4];
    const float ax = DT / fmaxf(tv.x, DT), ay = DT / fmaxf(tv.y, DT),
                az = DT / fmaxf(tv.z, DT), aw = DT / fmaxf(tv.w, DT);
    const float qx = 1.f - ax, qy = 1.f - ay, qz = 1.f - az, qw = 1.f - aw;
    const float4 sv = reinterpret_cast<const float4*>(S)[(size_t)chunk * N4 + ch4];
    float sx = sv.x, sy = sv.y, sz = sv.z, sw = sv.w;
    f32x4* o = reinterpret_cast<f32x4*>(out) + (size_t)chunk * 16 * N4 + ch4;
    #pragma unroll
    for (int t = 0; t < 16; ++t) {
        sx = fmaf(qx, sx, ax * x[t].x);
        sy = fmaf(qy, sy, ay * x[t].y);
        sz = fmaf(qz, sz, az * x[t].z);
        sw = fmaf(qw, sw, aw * x[t].w);
        f32x4 ov; ov.x = sx + bv.x; ov.y = sy + bv.y; ov.z = sz + bv.z; ov.w = sw + bv.w;
        __builtin_nontemporal_store(ov, &o[(size_t)t * N4]);
    }
}

__global__ void fol_naive(const float* __restrict__ in, const float* __restrict__ tau,
                          const float* __restrict__ bias, float* __restrict__ out,
                          int N, int T) {
    const int ch = blockIdx.x * blockDim.x + threadIdx.x;
    if (ch >= N) return;
    const float a = DT / fmaxf(tau[ch], DT);
    const float q = 1.f - a;
    const float b = bias[ch];
    float s = in[ch];
    for (int t = 0; t < T; ++t) {
        const float x = in[(size_t)t * N + ch];
        s = fmaf(q, s, a * x);
        out[(size_t)t * N + ch] = s + b;
    }
}

static void launch_fallback(const float* in, const float* tau, const float* bias,
                            float* out, float* B, int N, int T, size_t ws_size,
                            hipStream_t stream) {
    const bool vec_ok = (N % 4 == 0);
    if (vec_ok && T == 8192 && ((size_t)512 * N * sizeof(float)) <= ws_size) {
        const int C = 512, L = 16, N4 = N / 4;
        const dim3 blk(256);
        const dim3 g13((N4 + 255) / 256, C);
        fol_pass1_L16<<<g13, blk, 0, stream>>>(in, tau, B, N4);
        fol_pass2_pipe<<<dim3((N + 255) / 256), blk, 0, stream>>>(in, tau, B, N, C, L);
        fol_pass3_L16<<<g13, blk, 0, stream>>>(in, tau, bias, B, out, N4);
        return;
    }
    fol_naive<<<dim3((N + 255) / 256), dim3(256), 0, stream>>>(in, tau, bias, out, N, T);
}

extern "C" void kernel_launch(void* const* d_in, const int* in_sizes, int n_in,
                              void* d_out, int out_size, void* d_ws, size_t ws_size,
                              hipStream_t stream) {
    const float* in   = (const float*)d_in[0];
    const float* tau  = (const float*)d_in[1];
    const float* bias = (const float*)d_in[2];
    float* out = (float*)d_out;
    float* B   = (float*)d_ws;

    const int N = in_sizes[1];
    const int T = in_sizes[0] / N;

    // Fused cooperative path: L=32 rows/chunk, 1024-ch slices, grid <= 1024
    // blocks (4 blocks/CU co-resident at __launch_bounds__(256,4)).
    const int L = 32;
    if (N % 1024 == 0 && T % L == 0) {
        int N4 = N / 4;
        int C = T / L;
        int nSlice = N4 / 256;
        int nChBlk = N / 256;
        const bool fits = ((size_t)C * N * sizeof(float) <= ws_size) &&
                          (C % 16 == 0) && ((size_t)C * nSlice <= 1024) &&
                          (nChBlk <= C * nSlice);
        if (fits) {
            void* args[] = {(void*)&in, (void*)&tau, (void*)&bias, (void*)&out,
                            (void*)&B, (void*)&N4, (void*)&C, (void*)&L,
                            (void*)&nSlice, (void*)&nChBlk};
            hipError_t err = hipLaunchCooperativeKernel(
                reinterpret_cast<void*>(fol_fused), dim3(C * nSlice), dim3(256),
                args, 0, stream);
            if (err == hipSuccess) return;
            (void)hipGetLastError();  // clear error, fall back
        }
    }

    launch_fallback(in, tau, bias, out, B, N, T, ws_size, stream);
}

// Round 11
// 268.239 us; speedup vs baseline: 1.8395x; 1.8395x over previous
//
#include <hip/hip_runtime.h>

#define DT 0.01f

// Native 4-float vector for nontemporal builtins (HIP's float4 is a class
// type, which __builtin_nontemporal_store rejects).
typedef float f32x4 __attribute__((ext_vector_type(4)));

// ---- Pass 1 (L=16): per-chunk local aggregate, zero initial state ----------
__global__ __launch_bounds__(256) void fol_pass1_L16(
        const float* __restrict__ in, const float* __restrict__ tau,
        float* __restrict__ B, int N4) {
    const int chunk = blockIdx.y;
    const int ch4 = blockIdx.x * 256 + threadIdx.x;
    if (ch4 >= N4) return;

    // Issue ALL 16 row loads up front -> MLP of 16 per thread.
    const float4* p = reinterpret_cast<const float4*>(in) + (size_t)chunk * 16 * N4 + ch4;
    float4 x[16];
    #pragma unroll
    for (int t = 0; t < 16; ++t) x[t] = p[(size_t)t * N4];

    const float4 tv = reinterpret_cast<const float4*>(tau)[ch4];
    const float ax = DT / fmaxf(tv.x, DT), ay = DT / fmaxf(tv.y, DT),
                az = DT / fmaxf(tv.z, DT), aw = DT / fmaxf(tv.w, DT);
    const float qx = 1.f - ax, qy = 1.f - ay, qz = 1.f - az, qw = 1.f - aw;

    float sx = 0.f, sy = 0.f, sz = 0.f, sw = 0.f;
    #pragma unroll
    for (int t = 0; t < 16; ++t) {
        sx = fmaf(qx, sx, ax * x[t].x);
        sy = fmaf(qy, sy, ay * x[t].y);
        sz = fmaf(qz, sz, az * x[t].z);
        sw = fmaf(qw, sw, aw * x[t].w);
    }
    reinterpret_cast<float4*>(B)[(size_t)chunk * N4 + ch4] = make_float4(sx, sy, sz, sw);
}

// ---- Pass 2: sequential combine across chunks, software-pipelined ----------
// In-place B[c][n] (aggregate) -> S[c][n] (state entering chunk c).
// Loads for batch k+1 are issued before the FMA chain of batch k consumes
// batch k (all loads are independent of S) -> 32-deep MLP.
__global__ __launch_bounds__(256) void fol_pass2_pipe(
        const float* __restrict__ in, const float* __restrict__ tau,
        float* __restrict__ B, int N, int C, int L) {
    const int ch = blockIdx.x * 256 + threadIdx.x;
    if (ch >= N) return;
    const float a = DT / fmaxf(tau[ch], DT);
    const float q = 1.f - a;
    float qL = 1.f, b = q;
    int e = L;
    while (e) { if (e & 1) qL *= b; b *= b; e >>= 1; }

    float S = in[ch];  // s_0 = input[0]

    constexpr int BATCH = 32;
    float x[BATCH], xn[BATCH];
    #pragma unroll
    for (int j = 0; j < BATCH; ++j) x[j] = B[(size_t)j * N + ch];

    for (int cb = 0; cb < C; cb += BATCH) {
        const int nb = cb + BATCH;
        if (nb < C) {
            #pragma unroll
            for (int j = 0; j < BATCH; ++j) xn[j] = B[(size_t)(nb + j) * N + ch];
        }
        #pragma unroll
        for (int j = 0; j < BATCH; ++j) {
            B[(size_t)(cb + j) * N + ch] = S;     // publish chunk-entry state
            S = fmaf(qL, S, x[j]);                // advance one chunk
        }
        #pragma unroll
        for (int j = 0; j < BATCH; ++j) x[j] = xn[j];
    }
}

// ---- Pass 3 (L=16): rescan each chunk from its true start state ------------
__global__ __launch_bounds__(256) void fol_pass3_L16(
        const float* __restrict__ in, const float* __restrict__ tau,
        const float* __restrict__ bias, const float* __restrict__ S,
        float* __restrict__ out, int N4) {
    const int chunk = blockIdx.y;
    const int ch4 = blockIdx.x * 256 + threadIdx.x;
    if (ch4 >= N4) return;

    const float4* p = reinterpret_cast<const float4*>(in) + (size_t)chunk * 16 * N4 + ch4;
    float4 x[16];
    #pragma unroll
    for (int t = 0; t < 16; ++t) x[t] = p[(size_t)t * N4];

    const float4 tv = reinterpret_cast<const float4*>(tau)[ch4];
    const float4 bv = reinterpret_cast<const float4*>(bias)[ch4];
    const float ax = DT / fmaxf(tv.x, DT), ay = DT / fmaxf(tv.y, DT),
                az = DT / fmaxf(tv.z, DT), aw = DT / fmaxf(tv.w, DT);
    const float qx = 1.f - ax, qy = 1.f - ay, qz = 1.f - az, qw = 1.f - aw;

    const float4 sv = reinterpret_cast<const float4*>(S)[(size_t)chunk * N4 + ch4];
    float sx = sv.x, sy = sv.y, sz = sv.z, sw = sv.w;

    f32x4* o = reinterpret_cast<f32x4*>(out) + (size_t)chunk * 16 * N4 + ch4;
    #pragma unroll
    for (int t = 0; t < 16; ++t) {
        sx = fmaf(qx, sx, ax * x[t].x);
        sy = fmaf(qy, sy, ay * x[t].y);
        sz = fmaf(qz, sz, az * x[t].z);
        sw = fmaf(qw, sw, aw * x[t].w);
        // Nontemporal: output stream must not evict the L3-resident input
        // (re-read here) nor pollute L2.
        f32x4 ov; ov.x = sx + bv.x; ov.y = sy + bv.y; ov.z = sz + bv.z; ov.w = sw + bv.w;
        __builtin_nontemporal_store(ov, &o[(size_t)t * N4]);
    }
}

// ---- Fallback: naive thread-per-channel scan (odd shapes only) -------------
__global__ void fol_naive(const float* __restrict__ in, const float* __restrict__ tau,
                          const float* __restrict__ bias, float* __restrict__ out,
                          int N, int T) {
    const int ch = blockIdx.x * blockDim.x + threadIdx.x;
    if (ch >= N) return;
    const float a = DT / fmaxf(tau[ch], DT);
    const float q = 1.f - a;
    const float b = bias[ch];
    float s = in[ch];
    for (int t = 0; t < T; ++t) {
        const float x = in[(size_t)t * N + ch];
        s = fmaf(q, s, a * x);
        out[(size_t)t * N + ch] = s + b;
    }
}

extern "C" void kernel_launch(void* const* d_in, const int* in_sizes, int n_in,
                              void* d_out, int out_size, void* d_ws, size_t ws_size,
                              hipStream_t stream) {
    const float* in   = (const float*)d_in[0];
    const float* tau  = (const float*)d_in[1];
    const float* bias = (const float*)d_in[2];
    float* out = (float*)d_out;
    float* B   = (float*)d_ws;

    const int N = in_sizes[1];
    const int T = in_sizes[0] / N;

    const bool vec_ok = (N % 4 == 0);

    // Proven path (R7: 271 µs total, ~98 µs of kernels): C=512 chunks, L=16.
    if (vec_ok && T == 8192 && ((size_t)512 * N * sizeof(float)) <= ws_size) {
        const int C = 512, L = 16, N4 = N / 4;
        const dim3 blk(256);
        const dim3 g13((N4 + 255) / 256, C);
        fol_pass1_L16<<<g13, blk, 0, stream>>>(in, tau, B, N4);
        fol_pass2_pipe<<<dim3((N + 255) / 256), blk, 0, stream>>>(in, tau, B, N, C, L);
        fol_pass3_L16<<<g13, blk, 0, stream>>>(in, tau, bias, B, out, N4);
        return;
    }

    fol_naive<<<dim3((N + 255) / 256), dim3(256), 0, stream>>>(in, tau, bias, out, N, T);
}